// Round 3
// baseline (3703.002 us; speedup 1.0000x reference)
//
#include <hip/hip_runtime.h>
#include <math.h>

#define NN 50000
#define NE 800000
#define DD 64
#define N_GCN 30
#define N_GGC 8
#define NB ((NN + 255) / 256)

__device__ __forceinline__ float lane_bcast(float v, int k) {
    return __int_as_float(__builtin_amdgcn_readlane(__float_as_int(v), k));
}

// ---------------- graph prep ----------------

__global__ void hist_kernel(const int* __restrict__ dst, int* __restrict__ cnt) {
    int i = blockIdx.x * blockDim.x + threadIdx.x;
    if (i < NE) atomicAdd(&cnt[dst[i]], 1);
}

__global__ void dinv_kernel(const int* __restrict__ cnt, float* __restrict__ dinv) {
    int i = blockIdx.x * blockDim.x + threadIdx.x;
    if (i < NN) dinv[i] = rsqrtf((float)cnt[i] + 1.0f);
}

__global__ void scan1_kernel(const int* __restrict__ cnt, int* __restrict__ bsum) {
    __shared__ int s[256];
    int tid = threadIdx.x;
    int i = blockIdx.x * 256 + tid;
    s[tid] = (i < NN) ? cnt[i] : 0;
    __syncthreads();
    for (int off = 128; off > 0; off >>= 1) {
        if (tid < off) s[tid] += s[tid + off];
        __syncthreads();
    }
    if (tid == 0) bsum[blockIdx.x] = s[0];
}

__global__ void scan2_kernel(int* __restrict__ bsum) {
    if (threadIdx.x == 0 && blockIdx.x == 0) {
        int acc = 0;
        for (int b = 0; b < NB; b++) { int v = bsum[b]; bsum[b] = acc; acc += v; }
        bsum[NB] = acc;
    }
}

__global__ void scan3_kernel(const int* __restrict__ cnt, const int* __restrict__ bsum,
                             int* __restrict__ rowptr) {
    __shared__ int s[256];
    int tid = threadIdx.x;
    int i = blockIdx.x * 256 + tid;
    int v = (i < NN) ? cnt[i] : 0;
    s[tid] = v;
    __syncthreads();
    for (int off = 1; off < 256; off <<= 1) {
        int t = (tid >= off) ? s[tid - off] : 0;
        __syncthreads();
        s[tid] += t;
        __syncthreads();
    }
    if (i < NN) rowptr[i] = bsum[blockIdx.x] + s[tid] - v;
    if (i == NN - 1) rowptr[NN] = bsum[blockIdx.x] + s[tid];
}

// packed edge record: .x = src node, .y = bitcast(norm weight)
__global__ void fill_kernel(const int* __restrict__ src, const int* __restrict__ dst,
                            const float* __restrict__ dinv, const int* __restrict__ rowptr,
                            int* __restrict__ cur, int2* __restrict__ epk) {
    int i = blockIdx.x * blockDim.x + threadIdx.x;
    if (i >= NE) return;
    int s = src[i], d = dst[i];
    int pos = atomicAdd(&cur[d], 1);
    int idx = rowptr[d] + pos;
    float w = dinv[s] * dinv[d];
    epk[idx] = make_int2(s, __float_as_int(w));
}

// ---------------- weight prep (transposes) ----------------

__global__ void prep_weights(const float* __restrict__ lw, const float* __restrict__ gw,
                             const float* __restrict__ wih, const float* __restrict__ whh,
                             float* __restrict__ lin_wt, float* __restrict__ gcn_wt,
                             float* __restrict__ wih_t, float* __restrict__ whh_t) {
    int i = blockIdx.x * blockDim.x + threadIdx.x;
    if (i < 8192) {              // lin_wt[k*64+j] = lw[j*128+k], k<128, j<64
        int k = i >> 6, j = i & 63;
        lin_wt[k * 64 + j] = lw[j * 128 + k];
    }
    if (i < 122880) {            // gcn_wt[l][k][j] = gw[l][j][k]  (h @ W^T form)
        int l = i >> 12, r = i & 4095;
        int k = r >> 6, j = r & 63;
        gcn_wt[l * 4096 + k * 64 + j] = gw[l * 4096 + j * 64 + k];
    }
    if (i < 12288) {             // i = j*64+k, j<192, k<64
        int j = i >> 6, k = i & 63;
        wih_t[k * 192 + j] = wih[i];
        whh_t[k * 192 + j] = whh[i];
    }
}

// ---------------- init linear: h = relu(x @ lw^T + lb), K=128 ----------------

__global__ __launch_bounds__(256) void init_linear(const float* __restrict__ x,
                                                   const float* __restrict__ lin_wt,
                                                   const float* __restrict__ lb,
                                                   float* __restrict__ h) {
    int lane = threadIdx.x & 63;
    int wv = blockIdx.x * (blockDim.x >> 6) + (threadIdx.x >> 6);
    int nw = gridDim.x * (blockDim.x >> 6);
    float w[128];
#pragma unroll
    for (int k = 0; k < 128; k++) w[k] = lin_wt[k * 64 + lane];
    float b = lb[lane];
    for (int n = wv; n < NN; n += nw) {
        float x0 = x[n * 128 + lane];
        float x1 = x[n * 128 + 64 + lane];
        float a0 = b, a1 = 0.f, a2 = 0.f, a3 = 0.f;
#pragma unroll
        for (int k = 0; k < 64; k += 4) {
            a0 = fmaf(lane_bcast(x0, k), w[k], a0);
            a1 = fmaf(lane_bcast(x0, k + 1), w[k + 1], a1);
            a2 = fmaf(lane_bcast(x0, k + 2), w[k + 2], a2);
            a3 = fmaf(lane_bcast(x0, k + 3), w[k + 3], a3);
        }
#pragma unroll
        for (int k = 0; k < 64; k += 4) {
            a0 = fmaf(lane_bcast(x1, k), w[64 + k], a0);
            a1 = fmaf(lane_bcast(x1, k + 1), w[64 + k + 1], a1);
            a2 = fmaf(lane_bcast(x1, k + 2), w[64 + k + 2], a2);
            a3 = fmaf(lane_bcast(x1, k + 3), w[64 + k + 3], a3);
        }
        h[n * 64 + lane] = fmaxf((a0 + a1) + (a2 + a3), 0.0f);
    }
}

// ---------------- fused agg + matmul ----------------
// out[n][:] = ( gather_sum(hin) [+ dinv^2 * hin[n] if NORM] ) @ wt  [+ bias if NORM]
// wt in [k][j] layout.  Gather: lane = sub*16+q, sub = edge slot, q = dim quarter.
// After butterfly ALL lanes hold full aggregated row s as float4 (dims q*4..q*4+3).

template <bool NORM>
__global__ __launch_bounds__(256) void agg_fused(const float* __restrict__ hin,
                                                 const int* __restrict__ rowptr,
                                                 const int2* __restrict__ epk,
                                                 const float* __restrict__ dinv,
                                                 const float* __restrict__ wt,
                                                 const float* __restrict__ bias,
                                                 float* __restrict__ out) {
    int lane = threadIdx.x & 63;
    int sub = lane >> 4;
    int q = lane & 15;
    int wv = blockIdx.x * (blockDim.x >> 6) + (threadIdx.x >> 6);
    int nw = gridDim.x * (blockDim.x >> 6);

    float w[64];
#pragma unroll
    for (int k = 0; k < 64; k++) w[k] = wt[k * 64 + lane];

    for (int n = wv; n < NN; n += nw) {
        int e0 = rowptr[n], e1 = rowptr[n + 1];
        float ax = 0.f, ay = 0.f, az = 0.f, aw = 0.f;

        int e = e0 + sub;
        while (e + 4 < e1) {
            int2 p0 = epk[e];
            int2 p1 = epk[e + 4];
            float4 v0 = *(const float4*)&hin[(size_t)p0.x * 64 + q * 4];
            float4 v1 = *(const float4*)&hin[(size_t)p1.x * 64 + q * 4];
            float w0 = NORM ? __int_as_float(p0.y) : 1.0f;
            float w1 = NORM ? __int_as_float(p1.y) : 1.0f;
            ax = fmaf(w0, v0.x, ax); ay = fmaf(w0, v0.y, ay);
            az = fmaf(w0, v0.z, az); aw = fmaf(w0, v0.w, aw);
            ax = fmaf(w1, v1.x, ax); ay = fmaf(w1, v1.y, ay);
            az = fmaf(w1, v1.z, az); aw = fmaf(w1, v1.w, aw);
            e += 8;
        }
        if (e < e1) {
            int2 p0 = epk[e];
            float4 v0 = *(const float4*)&hin[(size_t)p0.x * 64 + q * 4];
            float w0 = NORM ? __int_as_float(p0.y) : 1.0f;
            ax = fmaf(w0, v0.x, ax); ay = fmaf(w0, v0.y, ay);
            az = fmaf(w0, v0.z, az); aw = fmaf(w0, v0.w, aw);
        }

        // butterfly over the 4 edge slots -> all lanes hold full sums
        ax += __shfl_xor(ax, 16); ay += __shfl_xor(ay, 16);
        az += __shfl_xor(az, 16); aw += __shfl_xor(aw, 16);
        ax += __shfl_xor(ax, 32); ay += __shfl_xor(ay, 32);
        az += __shfl_xor(az, 32); aw += __shfl_xor(aw, 32);

        if (NORM) {
            float di = dinv[n];
            float dd = di * di;
            float4 sv = *(const float4*)&hin[(size_t)n * 64 + q * 4];
            ax = fmaf(dd, sv.x, ax); ay = fmaf(dd, sv.y, ay);
            az = fmaf(dd, sv.z, az); aw = fmaf(dd, sv.w, aw);
        }

        // matmul epilogue: out[j=lane] = bias + sum_k s_k * w[k]
        // dim k lives at lane (k>>2), component (k&3)
        float acc0 = NORM ? bias[lane] : 0.0f;
        float acc1 = 0.f;
#pragma unroll
        for (int k = 0; k < 64; k += 4) {
            acc0 = fmaf(lane_bcast(ax, k >> 2), w[k], acc0);
            acc1 = fmaf(lane_bcast(ay, k >> 2), w[k + 1], acc1);
            acc0 = fmaf(lane_bcast(az, k >> 2), w[k + 2], acc0);
            acc1 = fmaf(lane_bcast(aw, k >> 2), w[k + 3], acc1);
        }
        out[(size_t)n * 64 + lane] = acc0 + acc1;
    }
}

// ---------------- GRU gate matmuls, chunked: task = (n, c), c in 0..2 --------
// gi[n][c*64+j] = bih[c*64+j] + sum_k t1[n][k] * wih_t[k][c*64+j]
// gh[n][c*64+j] = bhh[c*64+j] + sum_k  h[n][k] * whh_t[k][c*64+j]

__global__ __launch_bounds__(256) void gate_mm(const float* __restrict__ t1,
                                               const float* __restrict__ h,
                                               const float* __restrict__ wih_t,
                                               const float* __restrict__ whh_t,
                                               const float* __restrict__ bih,
                                               const float* __restrict__ bhh,
                                               float* __restrict__ gi,
                                               float* __restrict__ gh) {
    int lane = threadIdx.x & 63;
    int wv = blockIdx.x * (blockDim.x >> 6) + (threadIdx.x >> 6);
    int nt = gridDim.x * (blockDim.x >> 6);
    for (int t = wv; t < NN * 3; t += nt) {
        int c = t / NN;          // contiguous c ranges: waves in a block share c
        int n = t - c * NN;
        float wi[64], wh[64];
#pragma unroll
        for (int k = 0; k < 64; k++) {
            wi[k] = wih_t[k * 192 + c * 64 + lane];
            wh[k] = whh_t[k * 192 + c * 64 + lane];
        }
        float tv = t1[(size_t)n * 64 + lane];
        float hv = h[(size_t)n * 64 + lane];
        float ai = bih[c * 64 + lane];
        float ah = bhh[c * 64 + lane];
#pragma unroll
        for (int k = 0; k < 64; k++) {
            float b1 = lane_bcast(tv, k);
            float b2 = lane_bcast(hv, k);
            ai = fmaf(b1, wi[k], ai);
            ah = fmaf(b2, wh[k], ah);
        }
        gi[(size_t)n * 192 + c * 64 + lane] = ai;
        gh[(size_t)n * 192 + c * 64 + lane] = ah;
    }
}

// ---------------- elementwise GRU ----------------
// thread = (n, q): 4 dims via float4

__global__ __launch_bounds__(256) void gru_elem(const float* __restrict__ gi,
                                                const float* __restrict__ gh,
                                                const float* __restrict__ h,
                                                float* __restrict__ hout) {
    int i = blockIdx.x * blockDim.x + threadIdx.x;   // i in [0, NN*16)
    if (i >= NN * 16) return;
    int n = i >> 4, q = i & 15;
    size_t base = (size_t)n * 192 + q * 4;
    float4 ir = *(const float4*)&gi[base];
    float4 iz = *(const float4*)&gi[base + 64];
    float4 in_ = *(const float4*)&gi[base + 128];
    float4 hr = *(const float4*)&gh[base];
    float4 hz = *(const float4*)&gh[base + 64];
    float4 hn = *(const float4*)&gh[base + 128];
    float4 hv = *(const float4*)&h[(size_t)n * 64 + q * 4];
    float4 r, z, nn, o;
    r.x = 1.f / (1.f + expf(-(ir.x + hr.x)));
    r.y = 1.f / (1.f + expf(-(ir.y + hr.y)));
    r.z = 1.f / (1.f + expf(-(ir.z + hr.z)));
    r.w = 1.f / (1.f + expf(-(ir.w + hr.w)));
    z.x = 1.f / (1.f + expf(-(iz.x + hz.x)));
    z.y = 1.f / (1.f + expf(-(iz.y + hz.y)));
    z.z = 1.f / (1.f + expf(-(iz.z + hz.z)));
    z.w = 1.f / (1.f + expf(-(iz.w + hz.w)));
    nn.x = tanhf(in_.x + r.x * hn.x);
    nn.y = tanhf(in_.y + r.y * hn.y);
    nn.z = tanhf(in_.z + r.z * hn.z);
    nn.w = tanhf(in_.w + r.w * hn.w);
    o.x = (1.f - z.x) * nn.x + z.x * hv.x;
    o.y = (1.f - z.y) * nn.y + z.y * hv.y;
    o.z = (1.f - z.z) * nn.z + z.z * hv.z;
    o.w = (1.f - z.w) * nn.w + z.w * hv.w;
    *(float4*)&hout[(size_t)n * 64 + q * 4] = o;
}

// ---------------- launch ----------------

extern "C" void kernel_launch(void* const* d_in, const int* in_sizes, int n_in,
                              void* d_out, int out_size, void* d_ws, size_t ws_size,
                              hipStream_t stream) {
    const float* x   = (const float*)d_in[0];
    const int*   ei  = (const int*)d_in[1];
    const int*   src = ei;
    const int*   dst = ei + NE;
    const float* lw  = (const float*)d_in[2];
    const float* lb  = (const float*)d_in[3];
    const float* gw  = (const float*)d_in[4];
    const float* gb  = (const float*)d_in[5];
    const float* ggw = (const float*)d_in[6];   // [l][k][j], used as h @ W -> natural layout
    const float* wih = (const float*)d_in[7];
    const float* whh = (const float*)d_in[8];
    const float* bih = (const float*)d_in[9];
    const float* bhh = (const float*)d_in[10];
    float* outp = (float*)d_out;

    char* ws = (char*)d_ws;
    size_t off = 0;
    auto take = [&](size_t bytes) -> char* {
        char* p = ws + off;
        off += (bytes + 255) & ~(size_t)255;
        return p;
    };
    int*   cnt    = (int*)take(NN * 4);
    int*   cur    = (int*)take(NN * 4);
    int*   rowptr = (int*)take((NN + 1) * 4);
    int*   bsum   = (int*)take((NB + 1) * 4);
    float* dinv   = (float*)take(NN * 4);
    int2*  epk    = (int2*)take((size_t)NE * 8);
    float* lin_wt = (float*)take(8192 * 4);
    float* gcn_wt = (float*)take(122880 * 4);
    float* wih_t  = (float*)take(12288 * 4);
    float* whh_t  = (float*)take(12288 * 4);
    float* h      = (float*)take((size_t)NN * 64 * 4);
    float* t0     = (float*)take((size_t)NN * 64 * 4);   // GCN ping-pong + gh reuse
    float* t1     = (float*)take((size_t)NN * 64 * 4);
    float* gi     = (float*)take((size_t)NN * 192 * 4);
    float* gh     = (float*)take((size_t)NN * 192 * 4);
    (void)ws_size; (void)in_sizes; (void)n_in; (void)out_size;

    hipMemsetAsync(cnt, 0, NN * 4, stream);
    hipMemsetAsync(cur, 0, NN * 4, stream);

    hist_kernel<<<(NE + 255) / 256, 256, 0, stream>>>(dst, cnt);
    dinv_kernel<<<(NN + 255) / 256, 256, 0, stream>>>(cnt, dinv);
    scan1_kernel<<<NB, 256, 0, stream>>>(cnt, bsum);
    scan2_kernel<<<1, 64, 0, stream>>>(bsum);
    scan3_kernel<<<NB, 256, 0, stream>>>(cnt, bsum, rowptr);
    fill_kernel<<<(NE + 255) / 256, 256, 0, stream>>>(src, dst, dinv, rowptr, cur, epk);
    prep_weights<<<480, 256, 0, stream>>>(lw, gw, wih, whh, lin_wt, gcn_wt, wih_t, whh_t);

    init_linear<<<512, 256, 0, stream>>>(x, lin_wt, lb, h);

    // GCN: hnext = (A_norm @ hcur) @ W_l^T + b_l   (ping-pong h <-> t0)
    float* cur_h = h;
    float* nxt_h = t0;
    for (int l = 0; l < N_GCN; l++) {
        agg_fused<true><<<(NN + 3) / 4, 256, 0, stream>>>(cur_h, rowptr, epk, dinv,
                                                          gcn_wt + l * 4096, gb + l * 64, nxt_h);
        float* tmp = cur_h; cur_h = nxt_h; nxt_h = tmp;
    }
    // after 30 layers state is back in h (cur_h == h)

    for (int l = 0; l < N_GGC; l++) {
        // t1 = (A @ h) @ W_l
        agg_fused<false><<<(NN + 3) / 4, 256, 0, stream>>>(cur_h, rowptr, epk, nullptr,
                                                           ggw + l * 4096, nullptr, t1);
        gate_mm<<<37500, 256, 0, stream>>>(t1, cur_h, wih_t, whh_t, bih, bhh, gi, gh);
        float* hdst = (l == N_GGC - 1) ? outp : cur_h;
        gru_elem<<<(NN * 16 + 255) / 256, 256, 0, stream>>>(gi, gh, cur_h, hdst);
    }
}

// Round 4
// 2775.859 us; speedup vs baseline: 1.3340x; 1.3340x over previous
//
#include <hip/hip_runtime.h>
#include <math.h>

#define NN 50000
#define NE 800000
#define DD 64
#define N_GCN 30
#define N_GGC 8
#define NB ((NN + 255) / 256)

__device__ __forceinline__ float lane_bcast(float v, int k) {
    return __int_as_float(__builtin_amdgcn_readlane(__float_as_int(v), k));
}

// ---------------- graph prep ----------------

__global__ void hist_kernel(const int* __restrict__ dst, int* __restrict__ cnt) {
    int i = blockIdx.x * blockDim.x + threadIdx.x;
    if (i < NE) atomicAdd(&cnt[dst[i]], 1);
}

__global__ void dinv_kernel(const int* __restrict__ cnt, float* __restrict__ dinv) {
    int i = blockIdx.x * blockDim.x + threadIdx.x;
    if (i < NN) dinv[i] = rsqrtf((float)cnt[i] + 1.0f);
}

__global__ void scan1_kernel(const int* __restrict__ cnt, int* __restrict__ bsum) {
    __shared__ int s[256];
    int tid = threadIdx.x;
    int i = blockIdx.x * 256 + tid;
    s[tid] = (i < NN) ? cnt[i] : 0;
    __syncthreads();
    for (int off = 128; off > 0; off >>= 1) {
        if (tid < off) s[tid] += s[tid + off];
        __syncthreads();
    }
    if (tid == 0) bsum[blockIdx.x] = s[0];
}

__global__ void scan2_kernel(int* __restrict__ bsum) {
    if (threadIdx.x == 0 && blockIdx.x == 0) {
        int acc = 0;
        for (int b = 0; b < NB; b++) { int v = bsum[b]; bsum[b] = acc; acc += v; }
        bsum[NB] = acc;
    }
}

__global__ void scan3_kernel(const int* __restrict__ cnt, const int* __restrict__ bsum,
                             int* __restrict__ rowptr) {
    __shared__ int s[256];
    int tid = threadIdx.x;
    int i = blockIdx.x * 256 + tid;
    int v = (i < NN) ? cnt[i] : 0;
    s[tid] = v;
    __syncthreads();
    for (int off = 1; off < 256; off <<= 1) {
        int t = (tid >= off) ? s[tid - off] : 0;
        __syncthreads();
        s[tid] += t;
        __syncthreads();
    }
    if (i < NN) rowptr[i] = bsum[blockIdx.x] + s[tid] - v;
    if (i == NN - 1) rowptr[NN] = bsum[blockIdx.x] + s[tid];
}

// packed edge record: .x = src node, .y = bitcast(norm weight)
__global__ void fill_kernel(const int* __restrict__ src, const int* __restrict__ dst,
                            const float* __restrict__ dinv, const int* __restrict__ rowptr,
                            int* __restrict__ cur, int2* __restrict__ epk) {
    int i = blockIdx.x * blockDim.x + threadIdx.x;
    if (i >= NE) return;
    int s = src[i], d = dst[i];
    int pos = atomicAdd(&cur[d], 1);
    int idx = rowptr[d] + pos;
    float w = dinv[s] * dinv[d];
    epk[idx] = make_int2(s, __float_as_int(w));
}

// ---------------- weight prep (transposes) ----------------

__global__ void prep_weights(const float* __restrict__ lw, const float* __restrict__ gw,
                             const float* __restrict__ wih, const float* __restrict__ whh,
                             float* __restrict__ lin_wt, float* __restrict__ gcn_wt,
                             float* __restrict__ wih_t, float* __restrict__ whh_t) {
    int i = blockIdx.x * blockDim.x + threadIdx.x;
    if (i < 8192) {              // lin_wt[k*64+j] = lw[j*128+k], k<128, j<64
        int k = i >> 6, j = i & 63;
        lin_wt[k * 64 + j] = lw[j * 128 + k];
    }
    if (i < 122880) {            // gcn_wt[l][k][j] = gw[l][j][k]  (h @ W^T form)
        int l = i >> 12, r = i & 4095;
        int k = r >> 6, j = r & 63;
        gcn_wt[l * 4096 + k * 64 + j] = gw[l * 4096 + j * 64 + k];
    }
    if (i < 12288) {             // i = j*64+k, j<192, k<64
        int j = i >> 6, k = i & 63;
        wih_t[k * 192 + j] = wih[i];
        whh_t[k * 192 + j] = whh[i];
    }
}

// ---------------- init linear: h = relu(x @ lw^T + lb), K=128 ----------------

__global__ __launch_bounds__(256) void init_linear(const float* __restrict__ x,
                                                   const float* __restrict__ lin_wt,
                                                   const float* __restrict__ lb,
                                                   float* __restrict__ h) {
    int lane = threadIdx.x & 63;
    int wv = blockIdx.x * (blockDim.x >> 6) + (threadIdx.x >> 6);
    int nw = gridDim.x * (blockDim.x >> 6);
    float w[128];
#pragma unroll
    for (int k = 0; k < 128; k++) w[k] = lin_wt[k * 64 + lane];
    float b = lb[lane];
    for (int n = wv; n < NN; n += nw) {
        float x0 = x[n * 128 + lane];
        float x1 = x[n * 128 + 64 + lane];
        float a0 = b, a1 = 0.f, a2 = 0.f, a3 = 0.f;
#pragma unroll
        for (int k = 0; k < 64; k += 4) {
            a0 = fmaf(lane_bcast(x0, k), w[k], a0);
            a1 = fmaf(lane_bcast(x0, k + 1), w[k + 1], a1);
            a2 = fmaf(lane_bcast(x0, k + 2), w[k + 2], a2);
            a3 = fmaf(lane_bcast(x0, k + 3), w[k + 3], a3);
        }
#pragma unroll
        for (int k = 0; k < 64; k += 4) {
            a0 = fmaf(lane_bcast(x1, k), w[64 + k], a0);
            a1 = fmaf(lane_bcast(x1, k + 1), w[64 + k + 1], a1);
            a2 = fmaf(lane_bcast(x1, k + 2), w[64 + k + 2], a2);
            a3 = fmaf(lane_bcast(x1, k + 3), w[64 + k + 3], a3);
        }
        h[n * 64 + lane] = fmaxf((a0 + a1) + (a2 + a3), 0.0f);
    }
}

// ---------------- fused agg + matmul ----------------
// out[n][:] = ( gather_sum(hin) [+ dinv^2 * hin[n] if NORM] ) @ wt  [+ bias if NORM]
// wt in [k][j] layout.  Gather: lane = sub*16+q, sub = edge slot, q = dim quarter.
// Launch with FEW blocks (grid-stride): weight preload amortizes over ~8 nodes/wave.

template <bool NORM>
__global__ __launch_bounds__(256) void agg_fused(const float* __restrict__ hin,
                                                 const int* __restrict__ rowptr,
                                                 const int2* __restrict__ epk,
                                                 const float* __restrict__ dinv,
                                                 const float* __restrict__ wt,
                                                 const float* __restrict__ bias,
                                                 float* __restrict__ out) {
    int lane = threadIdx.x & 63;
    int sub = lane >> 4;
    int q = lane & 15;
    int wv = blockIdx.x * (blockDim.x >> 6) + (threadIdx.x >> 6);
    int nw = gridDim.x * (blockDim.x >> 6);

    float w[64];
#pragma unroll
    for (int k = 0; k < 64; k++) w[k] = wt[k * 64 + lane];

    for (int n = wv; n < NN; n += nw) {
        int e0 = rowptr[n], e1 = rowptr[n + 1];
        float ax = 0.f, ay = 0.f, az = 0.f, aw = 0.f;

        int e = e0 + sub;
        while (e + 4 < e1) {
            int2 p0 = epk[e];
            int2 p1 = epk[e + 4];
            float4 v0 = *(const float4*)&hin[(size_t)p0.x * 64 + q * 4];
            float4 v1 = *(const float4*)&hin[(size_t)p1.x * 64 + q * 4];
            float w0 = NORM ? __int_as_float(p0.y) : 1.0f;
            float w1 = NORM ? __int_as_float(p1.y) : 1.0f;
            ax = fmaf(w0, v0.x, ax); ay = fmaf(w0, v0.y, ay);
            az = fmaf(w0, v0.z, az); aw = fmaf(w0, v0.w, aw);
            ax = fmaf(w1, v1.x, ax); ay = fmaf(w1, v1.y, ay);
            az = fmaf(w1, v1.z, az); aw = fmaf(w1, v1.w, aw);
            e += 8;
        }
        if (e < e1) {
            int2 p0 = epk[e];
            float4 v0 = *(const float4*)&hin[(size_t)p0.x * 64 + q * 4];
            float w0 = NORM ? __int_as_float(p0.y) : 1.0f;
            ax = fmaf(w0, v0.x, ax); ay = fmaf(w0, v0.y, ay);
            az = fmaf(w0, v0.z, az); aw = fmaf(w0, v0.w, aw);
        }

        // butterfly over the 4 edge slots -> all lanes hold full sums
        ax += __shfl_xor(ax, 16); ay += __shfl_xor(ay, 16);
        az += __shfl_xor(az, 16); aw += __shfl_xor(aw, 16);
        ax += __shfl_xor(ax, 32); ay += __shfl_xor(ay, 32);
        az += __shfl_xor(az, 32); aw += __shfl_xor(aw, 32);

        if (NORM) {
            float di = dinv[n];
            float dd = di * di;
            float4 sv = *(const float4*)&hin[(size_t)n * 64 + q * 4];
            ax = fmaf(dd, sv.x, ax); ay = fmaf(dd, sv.y, ay);
            az = fmaf(dd, sv.z, az); aw = fmaf(dd, sv.w, aw);
        }

        // matmul epilogue: out[j=lane] = bias + sum_k s_k * w[k]
        float acc0 = NORM ? bias[lane] : 0.0f;
        float acc1 = 0.f;
#pragma unroll
        for (int k = 0; k < 64; k += 4) {
            acc0 = fmaf(lane_bcast(ax, k >> 2), w[k], acc0);
            acc1 = fmaf(lane_bcast(ay, k >> 2), w[k + 1], acc1);
            acc0 = fmaf(lane_bcast(az, k >> 2), w[k + 2], acc0);
            acc1 = fmaf(lane_bcast(aw, k >> 2), w[k + 3], acc1);
        }
        out[(size_t)n * 64 + lane] = acc0 + acc1;
    }
}

// ---------------- GRU gate matmuls: 6 wave-groups = {gi,gh} x {3 chunks} -----
// Each wave fixes (which, c), loads w[64]+bias ONCE, grid-strides nodes.
// gi[n][c*64+j] = bih[c*64+j] + sum_k t1[n][k] * wih_t[k][c*64+j]
// gh[n][c*64+j] = bhh[c*64+j] + sum_k  h[n][k] * whh_t[k][c*64+j]

__global__ __launch_bounds__(256) void gate_mm6(const float* __restrict__ t1,
                                                const float* __restrict__ h,
                                                const float* __restrict__ wih_t,
                                                const float* __restrict__ whh_t,
                                                const float* __restrict__ bih,
                                                const float* __restrict__ bhh,
                                                float* __restrict__ gi,
                                                float* __restrict__ gh) {
    int lane = threadIdx.x & 63;
    int wv = blockIdx.x * (blockDim.x >> 6) + (threadIdx.x >> 6);
    int nwv = gridDim.x * (blockDim.x >> 6);   // must be divisible by 6
    int wpg = nwv / 6;                          // waves per group
    int grp = wv / wpg;                         // 0..5
    int widx = wv - grp * wpg;                  // wave index within group

    const float* in   = (grp < 3) ? t1 : h;
    const float* wsrc = (grp < 3) ? wih_t : whh_t;
    const float* bsrc = (grp < 3) ? bih : bhh;
    float* outp       = (grp < 3) ? gi : gh;
    int c = (grp < 3) ? grp : grp - 3;

    float w[64];
#pragma unroll
    for (int k = 0; k < 64; k++) w[k] = wsrc[k * 192 + c * 64 + lane];
    float bb = bsrc[c * 64 + lane];

    for (int n = widx; n < NN; n += wpg) {
        float v = in[(size_t)n * 64 + lane];
        float a0 = bb, a1 = 0.f, a2 = 0.f, a3 = 0.f;
#pragma unroll
        for (int k = 0; k < 64; k += 4) {
            a0 = fmaf(lane_bcast(v, k), w[k], a0);
            a1 = fmaf(lane_bcast(v, k + 1), w[k + 1], a1);
            a2 = fmaf(lane_bcast(v, k + 2), w[k + 2], a2);
            a3 = fmaf(lane_bcast(v, k + 3), w[k + 3], a3);
        }
        outp[(size_t)n * 192 + c * 64 + lane] = (a0 + a1) + (a2 + a3);
    }
}

// ---------------- elementwise GRU ----------------

__global__ __launch_bounds__(256) void gru_elem(const float* __restrict__ gi,
                                                const float* __restrict__ gh,
                                                const float* __restrict__ h,
                                                float* __restrict__ hout) {
    int i = blockIdx.x * blockDim.x + threadIdx.x;   // i in [0, NN*16)
    if (i >= NN * 16) return;
    int n = i >> 4, q = i & 15;
    size_t base = (size_t)n * 192 + q * 4;
    float4 ir = *(const float4*)&gi[base];
    float4 iz = *(const float4*)&gi[base + 64];
    float4 in_ = *(const float4*)&gi[base + 128];
    float4 hr = *(const float4*)&gh[base];
    float4 hz = *(const float4*)&gh[base + 64];
    float4 hn = *(const float4*)&gh[base + 128];
    float4 hv = *(const float4*)&h[(size_t)n * 64 + q * 4];
    float4 r, z, nn, o;
    r.x = 1.f / (1.f + expf(-(ir.x + hr.x)));
    r.y = 1.f / (1.f + expf(-(ir.y + hr.y)));
    r.z = 1.f / (1.f + expf(-(ir.z + hr.z)));
    r.w = 1.f / (1.f + expf(-(ir.w + hr.w)));
    z.x = 1.f / (1.f + expf(-(iz.x + hz.x)));
    z.y = 1.f / (1.f + expf(-(iz.y + hz.y)));
    z.z = 1.f / (1.f + expf(-(iz.z + hz.z)));
    z.w = 1.f / (1.f + expf(-(iz.w + hz.w)));
    nn.x = tanhf(in_.x + r.x * hn.x);
    nn.y = tanhf(in_.y + r.y * hn.y);
    nn.z = tanhf(in_.z + r.z * hn.z);
    nn.w = tanhf(in_.w + r.w * hn.w);
    o.x = (1.f - z.x) * nn.x + z.x * hv.x;
    o.y = (1.f - z.y) * nn.y + z.y * hv.y;
    o.z = (1.f - z.z) * nn.z + z.z * hv.z;
    o.w = (1.f - z.w) * nn.w + z.w * hv.w;
    *(float4*)&hout[(size_t)n * 64 + q * 4] = o;
}

// ---------------- launch ----------------

extern "C" void kernel_launch(void* const* d_in, const int* in_sizes, int n_in,
                              void* d_out, int out_size, void* d_ws, size_t ws_size,
                              hipStream_t stream) {
    const float* x   = (const float*)d_in[0];
    const int*   ei  = (const int*)d_in[1];
    const int*   src = ei;
    const int*   dst = ei + NE;
    const float* lw  = (const float*)d_in[2];
    const float* lb  = (const float*)d_in[3];
    const float* gw  = (const float*)d_in[4];
    const float* gb  = (const float*)d_in[5];
    const float* ggw = (const float*)d_in[6];   // [l][k][j], used as h @ W -> natural layout
    const float* wih = (const float*)d_in[7];
    const float* whh = (const float*)d_in[8];
    const float* bih = (const float*)d_in[9];
    const float* bhh = (const float*)d_in[10];
    float* outp = (float*)d_out;

    char* ws = (char*)d_ws;
    size_t off = 0;
    auto take = [&](size_t bytes) -> char* {
        char* p = ws + off;
        off += (bytes + 255) & ~(size_t)255;
        return p;
    };
    int*   cnt    = (int*)take(NN * 4);
    int*   cur    = (int*)take(NN * 4);
    int*   rowptr = (int*)take((NN + 1) * 4);
    int*   bsum   = (int*)take((NB + 1) * 4);
    float* dinv   = (float*)take(NN * 4);
    int2*  epk    = (int2*)take((size_t)NE * 8);
    float* lin_wt = (float*)take(8192 * 4);
    float* gcn_wt = (float*)take(122880 * 4);
    float* wih_t  = (float*)take(12288 * 4);
    float* whh_t  = (float*)take(12288 * 4);
    float* h      = (float*)take((size_t)NN * 64 * 4);
    float* t0     = (float*)take((size_t)NN * 64 * 4);
    float* t1     = (float*)take((size_t)NN * 64 * 4);
    float* gi     = (float*)take((size_t)NN * 192 * 4);
    float* gh     = (float*)take((size_t)NN * 192 * 4);
    (void)ws_size; (void)in_sizes; (void)n_in; (void)out_size;

    hipMemsetAsync(cnt, 0, NN * 4, stream);
    hipMemsetAsync(cur, 0, NN * 4, stream);

    hist_kernel<<<(NE + 255) / 256, 256, 0, stream>>>(dst, cnt);
    dinv_kernel<<<(NN + 255) / 256, 256, 0, stream>>>(cnt, dinv);
    scan1_kernel<<<NB, 256, 0, stream>>>(cnt, bsum);
    scan2_kernel<<<1, 64, 0, stream>>>(bsum);
    scan3_kernel<<<NB, 256, 0, stream>>>(cnt, bsum, rowptr);
    fill_kernel<<<(NE + 255) / 256, 256, 0, stream>>>(src, dst, dinv, rowptr, cur, epk);
    prep_weights<<<480, 256, 0, stream>>>(lw, gw, wih, whh, lin_wt, gcn_wt, wih_t, whh_t);

    init_linear<<<512, 256, 0, stream>>>(x, lin_wt, lb, h);

    // GCN: hnext = (A_norm @ hcur) @ W_l^T + b_l   (ping-pong h <-> t0)
    float* cur_h = h;
    float* nxt_h = t0;
    for (int l = 0; l < N_GCN; l++) {
        agg_fused<true><<<1536, 256, 0, stream>>>(cur_h, rowptr, epk, dinv,
                                                  gcn_wt + l * 4096, gb + l * 64, nxt_h);
        float* tmp = cur_h; cur_h = nxt_h; nxt_h = tmp;
    }
    // after 30 layers state is back in h (cur_h == h)

    for (int l = 0; l < N_GGC; l++) {
        // t1 = (A @ h) @ W_l
        agg_fused<false><<<1536, 256, 0, stream>>>(cur_h, rowptr, epk, nullptr,
                                                   ggw + l * 4096, nullptr, t1);
        gate_mm6<<<1152, 256, 0, stream>>>(t1, cur_h, wih_t, whh_t, bih, bhh, gi, gh);
        float* hdst = (l == N_GGC - 1) ? outp : cur_h;
        gru_elem<<<(NN * 16 + 255) / 256, 256, 0, stream>>>(gi, gh, cur_h, hdst);
    }
}

// Round 5
// 2593.862 us; speedup vs baseline: 1.4276x; 1.0702x over previous
//
#include <hip/hip_runtime.h>
#include <math.h>

#define NN 50000
#define NE 800000
#define DD 64
#define N_GCN 30
#define N_GGC 8
#define NB ((NN + 255) / 256)
#define NPB 6   // nodes per block-iteration in gru_fused

__device__ __forceinline__ float lane_bcast(float v, int k) {
    return __int_as_float(__builtin_amdgcn_readlane(__float_as_int(v), k));
}

// ---------------- graph prep ----------------

__global__ void hist_kernel(const int* __restrict__ dst, int* __restrict__ cnt) {
    int i = blockIdx.x * blockDim.x + threadIdx.x;
    if (i < NE) atomicAdd(&cnt[dst[i]], 1);
}

__global__ void dinv_kernel(const int* __restrict__ cnt, float* __restrict__ dinv) {
    int i = blockIdx.x * blockDim.x + threadIdx.x;
    if (i < NN) dinv[i] = rsqrtf((float)cnt[i] + 1.0f);
}

__global__ void scan1_kernel(const int* __restrict__ cnt, int* __restrict__ bsum) {
    __shared__ int s[256];
    int tid = threadIdx.x;
    int i = blockIdx.x * 256 + tid;
    s[tid] = (i < NN) ? cnt[i] : 0;
    __syncthreads();
    for (int off = 128; off > 0; off >>= 1) {
        if (tid < off) s[tid] += s[tid + off];
        __syncthreads();
    }
    if (tid == 0) bsum[blockIdx.x] = s[0];
}

__global__ void scan2_kernel(int* __restrict__ bsum) {
    if (threadIdx.x == 0 && blockIdx.x == 0) {
        int acc = 0;
        for (int b = 0; b < NB; b++) { int v = bsum[b]; bsum[b] = acc; acc += v; }
        bsum[NB] = acc;
    }
}

__global__ void scan3_kernel(const int* __restrict__ cnt, const int* __restrict__ bsum,
                             int* __restrict__ rowptr) {
    __shared__ int s[256];
    int tid = threadIdx.x;
    int i = blockIdx.x * 256 + tid;
    int v = (i < NN) ? cnt[i] : 0;
    s[tid] = v;
    __syncthreads();
    for (int off = 1; off < 256; off <<= 1) {
        int t = (tid >= off) ? s[tid - off] : 0;
        __syncthreads();
        s[tid] += t;
        __syncthreads();
    }
    if (i < NN) rowptr[i] = bsum[blockIdx.x] + s[tid] - v;
    if (i == NN - 1) rowptr[NN] = bsum[blockIdx.x] + s[tid];
}

// packed edge record: .x = src node, .y = bitcast(norm weight)
__global__ void fill_kernel(const int* __restrict__ src, const int* __restrict__ dst,
                            const float* __restrict__ dinv, const int* __restrict__ rowptr,
                            int* __restrict__ cur, int2* __restrict__ epk) {
    int i = blockIdx.x * blockDim.x + threadIdx.x;
    if (i >= NE) return;
    int s = src[i], d = dst[i];
    int pos = atomicAdd(&cur[d], 1);
    int idx = rowptr[d] + pos;
    float w = dinv[s] * dinv[d];
    epk[idx] = make_int2(s, __float_as_int(w));
}

// ---------------- weight prep (transposes) ----------------

__global__ void prep_weights(const float* __restrict__ lw, const float* __restrict__ gw,
                             const float* __restrict__ wih, const float* __restrict__ whh,
                             float* __restrict__ lin_wt, float* __restrict__ gcn_wt,
                             float* __restrict__ wih_t, float* __restrict__ whh_t) {
    int i = blockIdx.x * blockDim.x + threadIdx.x;
    if (i < 8192) {              // lin_wt[k*64+j] = lw[j*128+k], k<128, j<64
        int k = i >> 6, j = i & 63;
        lin_wt[k * 64 + j] = lw[j * 128 + k];
    }
    if (i < 122880) {            // gcn_wt[l][k][j] = gw[l][j][k]  (s @ W^T form)
        int l = i >> 12, r = i & 4095;
        int k = r >> 6, j = r & 63;
        gcn_wt[l * 4096 + k * 64 + j] = gw[l * 4096 + j * 64 + k];
    }
    if (i < 12288) {             // i = j*64+k, j<192, k<64
        int j = i >> 6, k = i & 63;
        wih_t[k * 192 + j] = wih[i];
        whh_t[k * 192 + j] = whh[i];
    }
}

// ---------------- combined GGC weights ----------------
// WB[l][g][k][j], g<3: Wc_l[k][g*64+j] = sum_m ggw_l[k][m] * wih_t[m][g*64+j]
//                g>=3: whh_t[k][(g-3)*64+j]   (replicated per layer for uniform ptr)
// BB[0..191] = bih, BB[192..383] = bhh

__global__ void prep_comb(const float* __restrict__ ggw, const float* __restrict__ wih_t,
                          const float* __restrict__ whh_t, const float* __restrict__ bih,
                          const float* __restrict__ bhh,
                          float* __restrict__ WB, float* __restrict__ BB) {
    int tid = blockIdx.x * blockDim.x + threadIdx.x;
    int wv = tid >> 6, lane = tid & 63;
    if (wv < 24) {               // wv = l*3 + c
        int l = wv / 3, c = wv - l * 3;
        float u[64];
#pragma unroll
        for (int m = 0; m < 64; m++) u[m] = wih_t[m * 192 + c * 64 + lane];
        for (int k = 0; k < 64; k++) {
            float v = ggw[l * 4096 + k * 64 + lane];
            float a0 = 0.f, a1 = 0.f, a2 = 0.f, a3 = 0.f;
#pragma unroll
            for (int m = 0; m < 64; m += 4) {
                a0 = fmaf(lane_bcast(v, m), u[m], a0);
                a1 = fmaf(lane_bcast(v, m + 1), u[m + 1], a1);
                a2 = fmaf(lane_bcast(v, m + 2), u[m + 2], a2);
                a3 = fmaf(lane_bcast(v, m + 3), u[m + 3], a3);
            }
            WB[l * 24576 + c * 4096 + k * 64 + lane] = (a0 + a1) + (a2 + a3);
        }
    }
    // copy whh chunks: idx over l(8) x c(3) x k(64) x j(64)
    int nthr = blockDim.x * gridDim.x;
    for (int idx = tid; idx < 98304; idx += nthr) {
        int l = idx / 12288;
        int rem = idx - l * 12288;
        int c = rem >> 12;
        int r2 = rem & 4095;
        int k = r2 >> 6, j = r2 & 63;
        WB[l * 24576 + (3 + c) * 4096 + k * 64 + j] = whh_t[k * 192 + c * 64 + j];
    }
    if (tid < 384) BB[tid] = (tid < 192) ? bih[tid] : bhh[tid - 192];
}

// ---------------- init linear: h = relu(x @ lw^T + lb), K=128 ----------------

__global__ __launch_bounds__(256) void init_linear(const float* __restrict__ x,
                                                   const float* __restrict__ lin_wt,
                                                   const float* __restrict__ lb,
                                                   float* __restrict__ h) {
    int lane = threadIdx.x & 63;
    int wv = blockIdx.x * (blockDim.x >> 6) + (threadIdx.x >> 6);
    int nw = gridDim.x * (blockDim.x >> 6);
    float w[128];
#pragma unroll
    for (int k = 0; k < 128; k++) w[k] = lin_wt[k * 64 + lane];
    float b = lb[lane];
    for (int n = wv; n < NN; n += nw) {
        float x0 = x[n * 128 + lane];
        float x1 = x[n * 128 + 64 + lane];
        float a0 = b, a1 = 0.f, a2 = 0.f, a3 = 0.f;
#pragma unroll
        for (int k = 0; k < 64; k += 4) {
            a0 = fmaf(lane_bcast(x0, k), w[k], a0);
            a1 = fmaf(lane_bcast(x0, k + 1), w[k + 1], a1);
            a2 = fmaf(lane_bcast(x0, k + 2), w[k + 2], a2);
            a3 = fmaf(lane_bcast(x0, k + 3), w[k + 3], a3);
        }
#pragma unroll
        for (int k = 0; k < 64; k += 4) {
            a0 = fmaf(lane_bcast(x1, k), w[64 + k], a0);
            a1 = fmaf(lane_bcast(x1, k + 1), w[64 + k + 1], a1);
            a2 = fmaf(lane_bcast(x1, k + 2), w[64 + k + 2], a2);
            a3 = fmaf(lane_bcast(x1, k + 3), w[64 + k + 3], a3);
        }
        h[n * 64 + lane] = fmaxf((a0 + a1) + (a2 + a3), 0.0f);
    }
}

// ---------------- raw aggregation (no weights -> tiny VGPR, high occupancy) --
// out[n] = sum_edges w_e * hin[src]  (+ dinv[n]^2 * hin[n] if NORM)
// lane = sub*16 + q : sub = edge slot (0..3), q = dim quarter

template <bool NORM>
__global__ __launch_bounds__(256) void agg_raw(const float* __restrict__ hin,
                                               const int* __restrict__ rowptr,
                                               const int2* __restrict__ epk,
                                               const float* __restrict__ dinv,
                                               float* __restrict__ out) {
    int lane = threadIdx.x & 63;
    int sub = lane >> 4;
    int q = lane & 15;
    int wv = blockIdx.x * (blockDim.x >> 6) + (threadIdx.x >> 6);
    int nw = gridDim.x * (blockDim.x >> 6);

    for (int n = wv; n < NN; n += nw) {
        int e0 = rowptr[n], e1 = rowptr[n + 1];
        float ax = 0.f, ay = 0.f, az = 0.f, aw = 0.f;

        int e = e0 + sub;
        while (e + 4 < e1) {
            int2 p0 = epk[e];
            int2 p1 = epk[e + 4];
            float4 v0 = *(const float4*)&hin[(size_t)p0.x * 64 + q * 4];
            float4 v1 = *(const float4*)&hin[(size_t)p1.x * 64 + q * 4];
            float w0 = NORM ? __int_as_float(p0.y) : 1.0f;
            float w1 = NORM ? __int_as_float(p1.y) : 1.0f;
            ax = fmaf(w0, v0.x, ax); ay = fmaf(w0, v0.y, ay);
            az = fmaf(w0, v0.z, az); aw = fmaf(w0, v0.w, aw);
            ax = fmaf(w1, v1.x, ax); ay = fmaf(w1, v1.y, ay);
            az = fmaf(w1, v1.z, az); aw = fmaf(w1, v1.w, aw);
            e += 8;
        }
        if (e < e1) {
            int2 p0 = epk[e];
            float4 v0 = *(const float4*)&hin[(size_t)p0.x * 64 + q * 4];
            float w0 = NORM ? __int_as_float(p0.y) : 1.0f;
            ax = fmaf(w0, v0.x, ax); ay = fmaf(w0, v0.y, ay);
            az = fmaf(w0, v0.z, az); aw = fmaf(w0, v0.w, aw);
        }

        ax += __shfl_xor(ax, 16); ay += __shfl_xor(ay, 16);
        az += __shfl_xor(az, 16); aw += __shfl_xor(aw, 16);
        ax += __shfl_xor(ax, 32); ay += __shfl_xor(ay, 32);
        az += __shfl_xor(az, 32); aw += __shfl_xor(aw, 32);

        if (sub == 0) {
            float4 r;
            if (NORM) {
                float di = dinv[n];
                float dd = di * di;
                float4 sv = *(const float4*)&hin[(size_t)n * 64 + q * 4];
                r.x = fmaf(dd, sv.x, ax);
                r.y = fmaf(dd, sv.y, ay);
                r.z = fmaf(dd, sv.z, az);
                r.w = fmaf(dd, sv.w, aw);
            } else {
                r.x = ax; r.y = ay; r.z = az; r.w = aw;
            }
            *(float4*)&out[(size_t)n * 64 + q * 4] = r;
        }
    }
}

// ---------------- mm64b: out[n][j] = bias[j] + sum_k in[n][k] * wt[k][j] -----

__global__ __launch_bounds__(256) void mm64b(const float* __restrict__ in,
                                             const float* __restrict__ wt,
                                             const float* __restrict__ bias,
                                             float* __restrict__ out) {
    int lane = threadIdx.x & 63;
    int wv = blockIdx.x * (blockDim.x >> 6) + (threadIdx.x >> 6);
    int nw = gridDim.x * (blockDim.x >> 6);
    float w[64];
#pragma unroll
    for (int k = 0; k < 64; k++) w[k] = wt[k * 64 + lane];
    float b = bias[lane];
    for (int n = wv; n < NN; n += nw) {
        float hreg = in[(size_t)n * 64 + lane];
        float a0 = b, a1 = 0.f, a2 = 0.f, a3 = 0.f;
#pragma unroll
        for (int k = 0; k < 64; k += 4) {
            a0 = fmaf(lane_bcast(hreg, k), w[k], a0);
            a1 = fmaf(lane_bcast(hreg, k + 1), w[k + 1], a1);
            a2 = fmaf(lane_bcast(hreg, k + 2), w[k + 2], a2);
            a3 = fmaf(lane_bcast(hreg, k + 3), w[k + 3], a3);
        }
        out[(size_t)n * 64 + lane] = (a0 + a1) + (a2 + a3);
    }
}

// ---------------- fused GGC step: gates (LDS) + GRU blend, h in place --------
// block = 384 threads = 6 waves; wave g<3: gi chunk g from t1 (combined Wc);
// g>=3: gh chunk g-3 from h. Gates staged in LDS; then 384 threads blend 6 nodes.

__global__ __launch_bounds__(384) void gru_fused(const float* __restrict__ t1,
                                                 const float* __restrict__ h,
                                                 const float* __restrict__ WBl,
                                                 const float* __restrict__ BB,
                                                 float* __restrict__ hout) {
    __shared__ float lds[NPB * 384];
    int tid = threadIdx.x;
    int g = tid >> 6, lane = tid & 63;
    const float* wptr = WBl + (g << 12);
    float w[64];
#pragma unroll
    for (int k = 0; k < 64; k++) w[k] = wptr[k * 64 + lane];
    float bb = BB[g * 64 + lane];
    const float* in = (g < 3) ? t1 : h;

    for (int base = blockIdx.x * NPB; base < NN; base += gridDim.x * NPB) {
        for (int i = 0; i < NPB; i++) {
            int n = base + i;
            if (n < NN) {
                float v = in[(size_t)n * 64 + lane];
                float a0 = bb, a1 = 0.f, a2 = 0.f, a3 = 0.f;
#pragma unroll
                for (int k = 0; k < 64; k += 4) {
                    a0 = fmaf(lane_bcast(v, k), w[k], a0);
                    a1 = fmaf(lane_bcast(v, k + 1), w[k + 1], a1);
                    a2 = fmaf(lane_bcast(v, k + 2), w[k + 2], a2);
                    a3 = fmaf(lane_bcast(v, k + 3), w[k + 3], a3);
                }
                lds[i * 384 + g * 64 + lane] = (a0 + a1) + (a2 + a3);
            }
        }
        __syncthreads();
        // blend: thread's node slot = g, dim = lane
        int n2 = base + g;
        if (n2 < NN) {
            float ir = lds[g * 384 + lane];
            float iz = lds[g * 384 + 64 + lane];
            float inn = lds[g * 384 + 128 + lane];
            float hr = lds[g * 384 + 192 + lane];
            float hz = lds[g * 384 + 256 + lane];
            float hn = lds[g * 384 + 320 + lane];
            float hv = h[(size_t)n2 * 64 + lane];
            float r = 1.0f / (1.0f + __expf(-(ir + hr)));
            float z = 1.0f / (1.0f + __expf(-(iz + hz)));
            float targ = inn + r * hn;
            float t2 = __expf(2.0f * targ);
            float nn2 = 1.0f - 2.0f / (t2 + 1.0f);
            hout[(size_t)n2 * 64 + lane] = (1.0f - z) * nn2 + z * hv;
        }
        __syncthreads();
    }
}

// ---------------- launch ----------------

extern "C" void kernel_launch(void* const* d_in, const int* in_sizes, int n_in,
                              void* d_out, int out_size, void* d_ws, size_t ws_size,
                              hipStream_t stream) {
    const float* x   = (const float*)d_in[0];
    const int*   ei  = (const int*)d_in[1];
    const int*   src = ei;
    const int*   dst = ei + NE;
    const float* lw  = (const float*)d_in[2];
    const float* lb  = (const float*)d_in[3];
    const float* gw  = (const float*)d_in[4];
    const float* gb  = (const float*)d_in[5];
    const float* ggw = (const float*)d_in[6];   // [l][k][j] natural h@W layout
    const float* wih = (const float*)d_in[7];
    const float* whh = (const float*)d_in[8];
    const float* bih = (const float*)d_in[9];
    const float* bhh = (const float*)d_in[10];
    float* outp = (float*)d_out;

    char* ws = (char*)d_ws;
    size_t off = 0;
    auto take = [&](size_t bytes) -> char* {
        char* p = ws + off;
        off += (bytes + 255) & ~(size_t)255;
        return p;
    };
    int*   cnt    = (int*)take(NN * 4);
    int*   cur    = (int*)take(NN * 4);
    int*   rowptr = (int*)take((NN + 1) * 4);
    int*   bsum   = (int*)take((NB + 1) * 4);
    float* dinv   = (float*)take(NN * 4);
    int2*  epk    = (int2*)take((size_t)NE * 8);
    float* lin_wt = (float*)take(8192 * 4);
    float* gcn_wt = (float*)take(122880 * 4);
    float* wih_t  = (float*)take(12288 * 4);
    float* whh_t  = (float*)take(12288 * 4);
    float* WB     = (float*)take(196608 * 4);   // 8 layers x 6 groups x 64 x 64
    float* BB     = (float*)take(384 * 4);
    float* h      = (float*)take((size_t)NN * 64 * 4);
    float* t1     = (float*)take((size_t)NN * 64 * 4);
    (void)ws_size; (void)in_sizes; (void)n_in; (void)out_size;

    hipMemsetAsync(cnt, 0, NN * 4, stream);
    hipMemsetAsync(cur, 0, NN * 4, stream);

    hist_kernel<<<(NE + 255) / 256, 256, 0, stream>>>(dst, cnt);
    dinv_kernel<<<(NN + 255) / 256, 256, 0, stream>>>(cnt, dinv);
    scan1_kernel<<<NB, 256, 0, stream>>>(cnt, bsum);
    scan2_kernel<<<1, 64, 0, stream>>>(bsum);
    scan3_kernel<<<NB, 256, 0, stream>>>(cnt, bsum, rowptr);
    fill_kernel<<<(NE + 255) / 256, 256, 0, stream>>>(src, dst, dinv, rowptr, cur, epk);
    prep_weights<<<480, 256, 0, stream>>>(lw, gw, wih, whh, lin_wt, gcn_wt, wih_t, whh_t);
    prep_comb<<<96, 256, 0, stream>>>(ggw, wih_t, whh_t, bih, bhh, WB, BB);

    init_linear<<<512, 256, 0, stream>>>(x, lin_wt, lb, h);

    // GCN: t1 = A_norm @ h (raw, incl self-loop); h = t1 @ W^T + b
    for (int l = 0; l < N_GCN; l++) {
        agg_raw<true><<<12500, 256, 0, stream>>>(h, rowptr, epk, dinv, t1);
        mm64b<<<1024, 256, 0, stream>>>(t1, gcn_wt + l * 4096, gb + l * 64, h);
    }

    // GGC: t1 = A @ h (raw); gates+GRU fused (gi uses combined Wc_l)
    for (int l = 0; l < N_GGC; l++) {
        agg_raw<false><<<12500, 256, 0, stream>>>(h, rowptr, epk, nullptr, t1);
        float* hdst = (l == N_GGC - 1) ? outp : h;
        gru_fused<<<1024, 384, 0, stream>>>(t1, h, WB + l * 24576, BB, hdst);
    }
}